// Round 3
// baseline (1848.609 us; speedup 1.0000x reference)
//
#include <hip/hip_runtime.h>
#include <stdint.h>

typedef __bf16 bf16;
typedef __attribute__((ext_vector_type(8))) bf16 bf16x8;
typedef __attribute__((ext_vector_type(4))) bf16 bf16x4;
typedef __attribute__((ext_vector_type(4))) float f32x4;

#define T_DIM 512
#define H_DIM 4096
#define F_DIM 14336

// LDS layout: [rows][64] bf16, 128-B rows, XOR-swizzled (T2-style):
// elem index = r*64 + (c ^ ((r&7)<<3)).  2-way conflicts max (free).
__device__ __forceinline__ int swz(int r, int c) {
    return r * 64 + (c ^ ((r & 7) << 3));
}

// ---------------------------------------------------------------------------
__global__ void cvt_x_kernel(const float* __restrict__ x, bf16* __restrict__ xb) {
    int i = (blockIdx.x * 256 + threadIdx.x) * 4;
    float4 v = *(const float4*)(x + i);
    bf16x4 o = {(bf16)v.x, (bf16)v.y, (bf16)v.z, (bf16)v.w};
    *(bf16x4*)(xb + i) = o;
}

// ---------------------------------------------------------------------------
// Fused gate+up: inter = silu(x@W1^T) * (x@W3^T).
// Block: 256 thr (4 waves, 2Mx2N), tile 128(M) x 64(N), BK=64.
// grid = (M/128=4, F/64=224)  -> 896 blocks; x-fast so same-N blocks co-run (L3 dedup).
__global__ __launch_bounds__(256, 4)
void gemm_gateup(const bf16* __restrict__ A,
                 const int* __restrict__ Wq1, const float* __restrict__ Sc1,
                 const float* __restrict__ Zr1,
                 const int* __restrict__ Wq3, const float* __restrict__ Sc3,
                 const float* __restrict__ Zr3,
                 bf16* __restrict__ inter) {
    constexpr int KD = H_DIM;
    __shared__ __align__(16) bf16 As[128 * 64];
    __shared__ __align__(16) bf16 Bs1[64 * 64];
    __shared__ __align__(16) bf16 Bs3[64 * 64];

    const int tid  = threadIdx.x;
    const int lane = tid & 63;
    const int wid  = tid >> 6;
    const int wm   = wid >> 1;           // 0..1 (M half)
    const int wn   = wid & 1;            // 0..1 (N half)
    const int lr   = lane & 15;
    const int lk   = (lane >> 4) * 8;
    const int m0   = blockIdx.x * 128;
    const int n0   = blockIdx.y * 64;
    const int grp  = n0 >> 6;            // HQQ group (tile is 64-aligned)

    // A staging: thread covers rows {t>>2, +64} x k-chunks {(t&3)*8, +32}
    const int a_r = tid >> 2;
    const int a_c = (tid & 3) * 8;
    // B staging: thread covers rows (t>>4)*4 .. +3, k-range (t&15)*4 .. +3
    const int b_r = (tid >> 4) * 4;
    const int b_c = (tid & 15) * 4;

    f32x4 acc1[4][2], acc3[4][2];
    const f32x4 zf = {0.f, 0.f, 0.f, 0.f};
#pragma unroll
    for (int i = 0; i < 4; i++)
#pragma unroll
        for (int j = 0; j < 2; j++) { acc1[i][j] = zf; acc3[i][j] = zf; }

    bf16x8 areg[4];
    int4   q1r[4], q3r[4];
    float4 s1r, z1r, s3r, z3r;

#define LOAD_T(K0)                                                                \
    {                                                                             \
        _Pragma("unroll")                                                         \
        for (int p = 0; p < 2; p++)                                               \
            _Pragma("unroll")                                                     \
            for (int h = 0; h < 2; h++)                                           \
                areg[p * 2 + h] = *(const bf16x8*)(A + (size_t)(m0 + a_r + 64 * p) * KD + (K0) + a_c + 32 * h); \
        _Pragma("unroll")                                                         \
        for (int i = 0; i < 4; i++) {                                             \
            q1r[i] = *(const int4*)(Wq1 + (size_t)(n0 + b_r + i) * KD + (K0) + b_c); \
            q3r[i] = *(const int4*)(Wq3 + (size_t)(n0 + b_r + i) * KD + (K0) + b_c); \
        }                                                                         \
        s1r = *(const float4*)(Sc1 + (size_t)grp * KD + (K0) + b_c);              \
        z1r = *(const float4*)(Zr1 + (size_t)grp * KD + (K0) + b_c);              \
        s3r = *(const float4*)(Sc3 + (size_t)grp * KD + (K0) + b_c);              \
        z3r = *(const float4*)(Zr3 + (size_t)grp * KD + (K0) + b_c);              \
    }

    LOAD_T(0);

    for (int k0 = 0; k0 < KD; k0 += 64) {
        __syncthreads();   // all waves done reading LDS from previous step
#pragma unroll
        for (int p = 0; p < 2; p++)
#pragma unroll
            for (int h = 0; h < 2; h++)
                *(bf16x8*)&As[swz(a_r + 64 * p, a_c + 32 * h)] = areg[p * 2 + h];
#pragma unroll
        for (int i = 0; i < 4; i++) {
            bf16x4 v;
            v[0] = (bf16)(((float)q1r[i].x - z1r.x) * s1r.x);
            v[1] = (bf16)(((float)q1r[i].y - z1r.y) * s1r.y);
            v[2] = (bf16)(((float)q1r[i].z - z1r.z) * s1r.z);
            v[3] = (bf16)(((float)q1r[i].w - z1r.w) * s1r.w);
            *(bf16x4*)&Bs1[swz(b_r + i, b_c)] = v;
        }
#pragma unroll
        for (int i = 0; i < 4; i++) {
            bf16x4 v;
            v[0] = (bf16)(((float)q3r[i].x - z3r.x) * s3r.x);
            v[1] = (bf16)(((float)q3r[i].y - z3r.y) * s3r.y);
            v[2] = (bf16)(((float)q3r[i].z - z3r.z) * s3r.z);
            v[3] = (bf16)(((float)q3r[i].w - z3r.w) * s3r.w);
            *(bf16x4*)&Bs3[swz(b_r + i, b_c)] = v;
        }
        __syncthreads();

        if (k0 + 64 < KD) LOAD_T(k0 + 64);   // prefetch next tile (in flight during compute)

#pragma unroll
        for (int kk = 0; kk < 2; kk++) {
            bf16x8 af[4], b1[2], b3[2];
#pragma unroll
            for (int mi = 0; mi < 4; mi++)
                af[mi] = *(const bf16x8*)&As[swz(wm * 64 + mi * 16 + lr, kk * 32 + lk)];
#pragma unroll
            for (int ni = 0; ni < 2; ni++) {
                b1[ni] = *(const bf16x8*)&Bs1[swz(wn * 32 + ni * 16 + lr, kk * 32 + lk)];
                b3[ni] = *(const bf16x8*)&Bs3[swz(wn * 32 + ni * 16 + lr, kk * 32 + lk)];
            }
            __builtin_amdgcn_s_setprio(1);
#pragma unroll
            for (int mi = 0; mi < 4; mi++)
#pragma unroll
                for (int ni = 0; ni < 2; ni++) {
                    acc1[mi][ni] = __builtin_amdgcn_mfma_f32_16x16x32_bf16(af[mi], b1[ni], acc1[mi][ni], 0, 0, 0);
                    acc3[mi][ni] = __builtin_amdgcn_mfma_f32_16x16x32_bf16(af[mi], b3[ni], acc3[mi][ni], 0, 0, 0);
                }
            __builtin_amdgcn_s_setprio(0);
        }
    }
#undef LOAD_T

    // Epilogue: silu(gate)*up -> inter.  C/D: row=(lane>>4)*4+r, col=lane&15
    const int orow = (lane >> 4) * 4;
#pragma unroll
    for (int mi = 0; mi < 4; mi++)
#pragma unroll
        for (int ni = 0; ni < 2; ni++) {
#pragma unroll
            for (int r = 0; r < 4; r++) {
                int m = m0 + wm * 64 + mi * 16 + orow + r;
                int c = n0 + wn * 32 + ni * 16 + lr;
                float g = acc1[mi][ni][r];
                float u = acc3[mi][ni][r];
                float s = g / (1.0f + __expf(-g));
                inter[(size_t)m * F_DIM + c] = (bf16)(s * u);
            }
        }
}

// ---------------------------------------------------------------------------
// Down proj with split-K: partials[sk] = inter[:, ks:ke] @ W2[:, ks:ke]^T
// grid = (M/128=4, H/64=64, SK), block 256.
template<int SPLITK>
__global__ __launch_bounds__(256, 4)
void gemm_down(const bf16* __restrict__ A, const int* __restrict__ Wq,
               const float* __restrict__ Sc, const float* __restrict__ Zr,
               float* __restrict__ partials) {
    constexpr int KD = F_DIM;
    constexpr int KC = KD / SPLITK;
    __shared__ __align__(16) bf16 As[128 * 64];
    __shared__ __align__(16) bf16 Bs[64 * 64];

    const int tid  = threadIdx.x;
    const int lane = tid & 63;
    const int wid  = tid >> 6;
    const int wm   = wid >> 1;
    const int wn   = wid & 1;
    const int lr   = lane & 15;
    const int lk   = (lane >> 4) * 8;
    const int m0   = blockIdx.x * 128;
    const int n0   = blockIdx.y * 64;
    const int grp  = n0 >> 6;
    const int kbeg = blockIdx.z * KC;
    const int kend = kbeg + KC;

    const int a_r = tid >> 2;
    const int a_c = (tid & 3) * 8;
    const int b_r = (tid >> 4) * 4;
    const int b_c = (tid & 15) * 4;

    f32x4 acc[4][2];
    const f32x4 zf = {0.f, 0.f, 0.f, 0.f};
#pragma unroll
    for (int i = 0; i < 4; i++)
#pragma unroll
        for (int j = 0; j < 2; j++) acc[i][j] = zf;

    bf16x8 areg[4];
    int4   qr[4];
    float4 sr, zr;

#define LOAD_T(K0)                                                                \
    {                                                                             \
        _Pragma("unroll")                                                         \
        for (int p = 0; p < 2; p++)                                               \
            _Pragma("unroll")                                                     \
            for (int h = 0; h < 2; h++)                                           \
                areg[p * 2 + h] = *(const bf16x8*)(A + (size_t)(m0 + a_r + 64 * p) * KD + (K0) + a_c + 32 * h); \
        _Pragma("unroll")                                                         \
        for (int i = 0; i < 4; i++)                                               \
            qr[i] = *(const int4*)(Wq + (size_t)(n0 + b_r + i) * KD + (K0) + b_c); \
        sr = *(const float4*)(Sc + (size_t)grp * KD + (K0) + b_c);                \
        zr = *(const float4*)(Zr + (size_t)grp * KD + (K0) + b_c);                \
    }

    LOAD_T(kbeg);

    for (int k0 = kbeg; k0 < kend; k0 += 64) {
        __syncthreads();
#pragma unroll
        for (int p = 0; p < 2; p++)
#pragma unroll
            for (int h = 0; h < 2; h++)
                *(bf16x8*)&As[swz(a_r + 64 * p, a_c + 32 * h)] = areg[p * 2 + h];
#pragma unroll
        for (int i = 0; i < 4; i++) {
            bf16x4 v;
            v[0] = (bf16)(((float)qr[i].x - zr.x) * sr.x);
            v[1] = (bf16)(((float)qr[i].y - zr.y) * sr.y);
            v[2] = (bf16)(((float)qr[i].z - zr.z) * sr.z);
            v[3] = (bf16)(((float)qr[i].w - zr.w) * sr.w);
            *(bf16x4*)&Bs[swz(b_r + i, b_c)] = v;
        }
        __syncthreads();

        if (k0 + 64 < kend) LOAD_T(k0 + 64);

#pragma unroll
        for (int kk = 0; kk < 2; kk++) {
            bf16x8 af[4], bfr[2];
#pragma unroll
            for (int mi = 0; mi < 4; mi++)
                af[mi] = *(const bf16x8*)&As[swz(wm * 64 + mi * 16 + lr, kk * 32 + lk)];
#pragma unroll
            for (int ni = 0; ni < 2; ni++)
                bfr[ni] = *(const bf16x8*)&Bs[swz(wn * 32 + ni * 16 + lr, kk * 32 + lk)];
            __builtin_amdgcn_s_setprio(1);
#pragma unroll
            for (int mi = 0; mi < 4; mi++)
#pragma unroll
                for (int ni = 0; ni < 2; ni++)
                    acc[mi][ni] = __builtin_amdgcn_mfma_f32_16x16x32_bf16(af[mi], bfr[ni], acc[mi][ni], 0, 0, 0);
            __builtin_amdgcn_s_setprio(0);
        }
    }
#undef LOAD_T

    float* po = partials + (size_t)blockIdx.z * T_DIM * H_DIM;
    const int orow = (lane >> 4) * 4;
#pragma unroll
    for (int mi = 0; mi < 4; mi++)
#pragma unroll
        for (int ni = 0; ni < 2; ni++) {
#pragma unroll
            for (int r = 0; r < 4; r++) {
                int m = m0 + wm * 64 + mi * 16 + orow + r;
                int c = n0 + wn * 32 + ni * 16 + lr;
                po[(size_t)m * H_DIM + c] = acc[mi][ni][r];
            }
        }
}

// ---------------------------------------------------------------------------
template<int S>
__global__ void reduce_kernel(const float* __restrict__ partials, float* __restrict__ out) {
    size_t i = ((size_t)blockIdx.x * 256 + threadIdx.x) * 4;
    f32x4 a = *(const f32x4*)(partials + i);
#pragma unroll
    for (int s = 1; s < S; s++)
        a += *(const f32x4*)(partials + (size_t)s * T_DIM * H_DIM + i);
    *(f32x4*)(out + i) = a;
}

// ---------------------------------------------------------------------------
extern "C" void kernel_launch(void* const* d_in, const int* in_sizes, int n_in,
                              void* d_out, int out_size, void* d_ws, size_t ws_size,
                              hipStream_t stream) {
    const float* x   = (const float*)d_in[0];
    const int*   w1q = (const int*)d_in[1];
    const float* w1s = (const float*)d_in[2];
    const float* w1z = (const float*)d_in[3];
    const int*   w2q = (const int*)d_in[4];
    const float* w2s = (const float*)d_in[5];
    const float* w2z = (const float*)d_in[6];
    const int*   w3q = (const int*)d_in[7];
    const float* w3s = (const float*)d_in[8];
    const float* w3z = (const float*)d_in[9];

    bf16*  xb    = (bf16*)d_ws;                         // [512][4096]  bf16 (4 MB)
    bf16*  inter = xb + (size_t)T_DIM * H_DIM;          // [512][14336] bf16 (14.7 MB)
    float* parts = (float*)(inter + (size_t)T_DIM * F_DIM);

    const size_t base   = (size_t)T_DIM * H_DIM * 2 + (size_t)T_DIM * F_DIM * 2;
    const size_t pbytes = (size_t)T_DIM * H_DIM * 4;

    cvt_x_kernel<<<dim3(2048), dim3(256), 0, stream>>>(x, xb);

    gemm_gateup<<<dim3(4, F_DIM / 64), dim3(256), 0, stream>>>(
        xb, w1q, w1s, w1z, w3q, w3s, w3z, inter);

    if (ws_size >= base + 4 * pbytes) {
        gemm_down<4><<<dim3(4, H_DIM / 64, 4), dim3(256), 0, stream>>>(inter, w2q, w2s, w2z, parts);
        reduce_kernel<4><<<dim3(2048), dim3(256), 0, stream>>>(parts, (float*)d_out);
    } else if (ws_size >= base + 2 * pbytes) {
        gemm_down<2><<<dim3(4, H_DIM / 64, 2), dim3(256), 0, stream>>>(inter, w2q, w2s, w2z, parts);
        reduce_kernel<2><<<dim3(2048), dim3(256), 0, stream>>>(parts, (float*)d_out);
    } else {
        gemm_down<1><<<dim3(4, H_DIM / 64, 1), dim3(256), 0, stream>>>(inter, w2q, w2s, w2z, parts);
        reduce_kernel<1><<<dim3(2048), dim3(256), 0, stream>>>(parts, (float*)d_out);
    }
}

// Round 4
// 490.975 us; speedup vs baseline: 3.7652x; 3.7652x over previous
//
#include <hip/hip_runtime.h>
#include <stdint.h>

typedef __bf16 bf16;
typedef __attribute__((ext_vector_type(8))) bf16 bf16x8;
typedef __attribute__((ext_vector_type(4))) bf16 bf16x4;
typedef __attribute__((ext_vector_type(4))) float f32x4;

#define T_DIM 512
#define H_DIM 4096
#define F_DIM 14336

// LDS layout: [rows][64] bf16, 128-B rows, XOR-swizzled:
// elem index = r*64 + (c ^ ((r&7)<<3)).  Spreads 16-row column reads over 8 slots.
__device__ __forceinline__ int swz(int r, int c) {
    return r * 64 + (c ^ ((r & 7) << 3));
}

// ---------------------------------------------------------------------------
__global__ void cvt_x_kernel(const float* __restrict__ x, bf16* __restrict__ xb) {
    int i = (blockIdx.x * 256 + threadIdx.x) * 4;
    float4 v = *(const float4*)(x + i);
    bf16x4 o = {(bf16)v.x, (bf16)v.y, (bf16)v.z, (bf16)v.w};
    *(bf16x4*)(xb + i) = o;
}

// ---------------------------------------------------------------------------
// Fused gate+up: inter = silu(x@W1^T) * (x@W3^T).
// Block: 256 thr (4 waves, 2Mx2N), tile 128(M) x 64(N), BK=64.
// grid = (M/128=4, F/64=224) -> 896 blocks, x-fast so M-replicas co-timed (L3 dedup).
__global__ __launch_bounds__(256, 2)
void gemm_gateup(const bf16* __restrict__ A,
                 const int* __restrict__ Wq1, const float* __restrict__ Sc1,
                 const float* __restrict__ Zr1,
                 const int* __restrict__ Wq3, const float* __restrict__ Sc3,
                 const float* __restrict__ Zr3,
                 bf16* __restrict__ inter) {
    constexpr int KD = H_DIM;
    __shared__ __align__(16) bf16 As[128 * 64];
    __shared__ __align__(16) bf16 Bs1[64 * 64];
    __shared__ __align__(16) bf16 Bs3[64 * 64];

    const int tid  = threadIdx.x;
    const int lane = tid & 63;
    const int wid  = tid >> 6;
    const int wm   = wid >> 1;           // 0..1 (M half)
    const int wn   = wid & 1;            // 0..1 (N half)
    const int lr   = lane & 15;
    const int lk   = (lane >> 4) * 8;
    const int m0   = blockIdx.x * 128;
    const int n0   = blockIdx.y * 64;
    const int grp  = n0 >> 6;            // HQQ group (tile is 64-aligned)

    // A staging: thread covers rows {t>>2, +64} x k-chunks {(t&3)*8, +32}
    const int a_r = tid >> 2;
    const int a_c = (tid & 3) * 8;
    // B staging: thread covers rows (t>>4)*4 .. +3, k-range (t&15)*4 .. +3
    const int b_r = (tid >> 4) * 4;
    const int b_c = (tid & 15) * 4;

    f32x4 acc1[4][2], acc3[4][2];
    const f32x4 zf = {0.f, 0.f, 0.f, 0.f};
#pragma unroll
    for (int i = 0; i < 4; i++)
#pragma unroll
        for (int j = 0; j < 2; j++) { acc1[i][j] = zf; acc3[i][j] = zf; }

    bf16x8 areg[4];
    int4   q1r[4], q3r[4];
    float4 s1r, z1r, s3r, z3r;

#define LOAD_T(K0)                                                                \
    {                                                                             \
        _Pragma("unroll")                                                         \
        for (int p = 0; p < 2; p++)                                               \
            _Pragma("unroll")                                                     \
            for (int h = 0; h < 2; h++)                                           \
                areg[p * 2 + h] = *(const bf16x8*)(A + (size_t)(m0 + a_r + 64 * p) * KD + (K0) + a_c + 32 * h); \
        _Pragma("unroll")                                                         \
        for (int i = 0; i < 4; i++) {                                             \
            q1r[i] = *(const int4*)(Wq1 + (size_t)(n0 + b_r + i) * KD + (K0) + b_c); \
            q3r[i] = *(const int4*)(Wq3 + (size_t)(n0 + b_r + i) * KD + (K0) + b_c); \
        }                                                                         \
        s1r = *(const float4*)(Sc1 + (size_t)grp * KD + (K0) + b_c);              \
        z1r = *(const float4*)(Zr1 + (size_t)grp * KD + (K0) + b_c);              \
        s3r = *(const float4*)(Sc3 + (size_t)grp * KD + (K0) + b_c);              \
        z3r = *(const float4*)(Zr3 + (size_t)grp * KD + (K0) + b_c);              \
    }

    LOAD_T(0);

    for (int k0 = 0; k0 < KD; k0 += 64) {
        __syncthreads();
#pragma unroll
        for (int p = 0; p < 2; p++)
#pragma unroll
            for (int h = 0; h < 2; h++)
                *(bf16x8*)&As[swz(a_r + 64 * p, a_c + 32 * h)] = areg[p * 2 + h];
#pragma unroll
        for (int i = 0; i < 4; i++) {
            bf16x4 v;
            v[0] = (bf16)(((float)q1r[i].x - z1r.x) * s1r.x);
            v[1] = (bf16)(((float)q1r[i].y - z1r.y) * s1r.y);
            v[2] = (bf16)(((float)q1r[i].z - z1r.z) * s1r.z);
            v[3] = (bf16)(((float)q1r[i].w - z1r.w) * s1r.w);
            *(bf16x4*)&Bs1[swz(b_r + i, b_c)] = v;
        }
#pragma unroll
        for (int i = 0; i < 4; i++) {
            bf16x4 v;
            v[0] = (bf16)(((float)q3r[i].x - z3r.x) * s3r.x);
            v[1] = (bf16)(((float)q3r[i].y - z3r.y) * s3r.y);
            v[2] = (bf16)(((float)q3r[i].z - z3r.z) * s3r.z);
            v[3] = (bf16)(((float)q3r[i].w - z3r.w) * s3r.w);
            *(bf16x4*)&Bs3[swz(b_r + i, b_c)] = v;
        }
        __syncthreads();

        if (k0 + 64 < KD) LOAD_T(k0 + 64);   // prefetch next tile during compute

#pragma unroll
        for (int kk = 0; kk < 2; kk++) {
            bf16x8 af[4], b1[2], b3[2];
#pragma unroll
            for (int mi = 0; mi < 4; mi++)
                af[mi] = *(const bf16x8*)&As[swz(wm * 64 + mi * 16 + lr, kk * 32 + lk)];
#pragma unroll
            for (int ni = 0; ni < 2; ni++) {
                b1[ni] = *(const bf16x8*)&Bs1[swz(wn * 32 + ni * 16 + lr, kk * 32 + lk)];
                b3[ni] = *(const bf16x8*)&Bs3[swz(wn * 32 + ni * 16 + lr, kk * 32 + lk)];
            }
#pragma unroll
            for (int mi = 0; mi < 4; mi++)
#pragma unroll
                for (int ni = 0; ni < 2; ni++) {
                    acc1[mi][ni] = __builtin_amdgcn_mfma_f32_16x16x32_bf16(af[mi], b1[ni], acc1[mi][ni], 0, 0, 0);
                    acc3[mi][ni] = __builtin_amdgcn_mfma_f32_16x16x32_bf16(af[mi], b3[ni], acc3[mi][ni], 0, 0, 0);
                }
        }
    }
#undef LOAD_T

    // Epilogue: silu(gate)*up -> inter.  C/D: row=(lane>>4)*4+r, col=lane&15
    const int orow = (lane >> 4) * 4;
#pragma unroll
    for (int mi = 0; mi < 4; mi++)
#pragma unroll
        for (int ni = 0; ni < 2; ni++) {
#pragma unroll
            for (int r = 0; r < 4; r++) {
                int m = m0 + wm * 64 + mi * 16 + orow + r;
                int c = n0 + wn * 32 + ni * 16 + lr;
                float g = acc1[mi][ni][r];
                float u = acc3[mi][ni][r];
                float s = g / (1.0f + __expf(-g));
                inter[(size_t)m * F_DIM + c] = (bf16)(s * u);
            }
        }
}

// ---------------------------------------------------------------------------
// Down proj with split-K: partials[sk] = inter[:, ks:ke] @ W2[:, ks:ke]^T
// grid = (M/128=4, H/64=64, SK), block 256.
template<int SPLITK>
__global__ __launch_bounds__(256, 2)
void gemm_down(const bf16* __restrict__ A, const int* __restrict__ Wq,
               const float* __restrict__ Sc, const float* __restrict__ Zr,
               float* __restrict__ partials) {
    constexpr int KD = F_DIM;
    constexpr int KC = KD / SPLITK;
    __shared__ __align__(16) bf16 As[128 * 64];
    __shared__ __align__(16) bf16 Bs[64 * 64];

    const int tid  = threadIdx.x;
    const int lane = tid & 63;
    const int wid  = tid >> 6;
    const int wm   = wid >> 1;
    const int wn   = wid & 1;
    const int lr   = lane & 15;
    const int lk   = (lane >> 4) * 8;
    const int m0   = blockIdx.x * 128;
    const int n0   = blockIdx.y * 64;
    const int grp  = n0 >> 6;
    const int kbeg = blockIdx.z * KC;
    const int kend = kbeg + KC;

    const int a_r = tid >> 2;
    const int a_c = (tid & 3) * 8;
    const int b_r = (tid >> 4) * 4;
    const int b_c = (tid & 15) * 4;

    f32x4 acc[4][2];
    const f32x4 zf = {0.f, 0.f, 0.f, 0.f};
#pragma unroll
    for (int i = 0; i < 4; i++)
#pragma unroll
        for (int j = 0; j < 2; j++) acc[i][j] = zf;

    bf16x8 areg[4];
    int4   qr[4];
    float4 sr, zr;

#define LOAD_T(K0)                                                                \
    {                                                                             \
        _Pragma("unroll")                                                         \
        for (int p = 0; p < 2; p++)                                               \
            _Pragma("unroll")                                                     \
            for (int h = 0; h < 2; h++)                                           \
                areg[p * 2 + h] = *(const bf16x8*)(A + (size_t)(m0 + a_r + 64 * p) * KD + (K0) + a_c + 32 * h); \
        _Pragma("unroll")                                                         \
        for (int i = 0; i < 4; i++)                                               \
            qr[i] = *(const int4*)(Wq + (size_t)(n0 + b_r + i) * KD + (K0) + b_c); \
        sr = *(const float4*)(Sc + (size_t)grp * KD + (K0) + b_c);                \
        zr = *(const float4*)(Zr + (size_t)grp * KD + (K0) + b_c);                \
    }

    LOAD_T(kbeg);

    for (int k0 = kbeg; k0 < kend; k0 += 64) {
        __syncthreads();
#pragma unroll
        for (int p = 0; p < 2; p++)
#pragma unroll
            for (int h = 0; h < 2; h++)
                *(bf16x8*)&As[swz(a_r + 64 * p, a_c + 32 * h)] = areg[p * 2 + h];
#pragma unroll
        for (int i = 0; i < 4; i++) {
            bf16x4 v;
            v[0] = (bf16)(((float)qr[i].x - zr.x) * sr.x);
            v[1] = (bf16)(((float)qr[i].y - zr.y) * sr.y);
            v[2] = (bf16)(((float)qr[i].z - zr.z) * sr.z);
            v[3] = (bf16)(((float)qr[i].w - zr.w) * sr.w);
            *(bf16x4*)&Bs[swz(b_r + i, b_c)] = v;
        }
        __syncthreads();

        if (k0 + 64 < kend) LOAD_T(k0 + 64);

#pragma unroll
        for (int kk = 0; kk < 2; kk++) {
            bf16x8 af[4], bfr[2];
#pragma unroll
            for (int mi = 0; mi < 4; mi++)
                af[mi] = *(const bf16x8*)&As[swz(wm * 64 + mi * 16 + lr, kk * 32 + lk)];
#pragma unroll
            for (int ni = 0; ni < 2; ni++)
                bfr[ni] = *(const bf16x8*)&Bs[swz(wn * 32 + ni * 16 + lr, kk * 32 + lk)];
#pragma unroll
            for (int mi = 0; mi < 4; mi++)
#pragma unroll
                for (int ni = 0; ni < 2; ni++)
                    acc[mi][ni] = __builtin_amdgcn_mfma_f32_16x16x32_bf16(af[mi], bfr[ni], acc[mi][ni], 0, 0, 0);
        }
    }
#undef LOAD_T

    float* po = partials + (size_t)blockIdx.z * T_DIM * H_DIM;
    const int orow = (lane >> 4) * 4;
#pragma unroll
    for (int mi = 0; mi < 4; mi++)
#pragma unroll
        for (int ni = 0; ni < 2; ni++) {
#pragma unroll
            for (int r = 0; r < 4; r++) {
                int m = m0 + wm * 64 + mi * 16 + orow + r;
                int c = n0 + wn * 32 + ni * 16 + lr;
                po[(size_t)m * H_DIM + c] = acc[mi][ni][r];
            }
        }
}

// ---------------------------------------------------------------------------
template<int S>
__global__ void reduce_kernel(const float* __restrict__ partials, float* __restrict__ out) {
    size_t i = ((size_t)blockIdx.x * 256 + threadIdx.x) * 4;
    f32x4 a = *(const f32x4*)(partials + i);
#pragma unroll
    for (int s = 1; s < S; s++)
        a += *(const f32x4*)(partials + (size_t)s * T_DIM * H_DIM + i);
    *(f32x4*)(out + i) = a;
}

// ---------------------------------------------------------------------------
extern "C" void kernel_launch(void* const* d_in, const int* in_sizes, int n_in,
                              void* d_out, int out_size, void* d_ws, size_t ws_size,
                              hipStream_t stream) {
    const float* x   = (const float*)d_in[0];
    const int*   w1q = (const int*)d_in[1];
    const float* w1s = (const float*)d_in[2];
    const float* w1z = (const float*)d_in[3];
    const int*   w2q = (const int*)d_in[4];
    const float* w2s = (const float*)d_in[5];
    const float* w2z = (const float*)d_in[6];
    const int*   w3q = (const int*)d_in[7];
    const float* w3s = (const float*)d_in[8];
    const float* w3z = (const float*)d_in[9];

    bf16*  xb    = (bf16*)d_ws;                         // [512][4096]  bf16 (4 MB)
    bf16*  inter = xb + (size_t)T_DIM * H_DIM;          // [512][14336] bf16 (14.7 MB)
    float* parts = (float*)(inter + (size_t)T_DIM * F_DIM);

    const size_t base   = (size_t)T_DIM * H_DIM * 2 + (size_t)T_DIM * F_DIM * 2;
    const size_t pbytes = (size_t)T_DIM * H_DIM * 4;

    cvt_x_kernel<<<dim3(2048), dim3(256), 0, stream>>>(x, xb);

    gemm_gateup<<<dim3(4, F_DIM / 64), dim3(256), 0, stream>>>(
        xb, w1q, w1s, w1z, w3q, w3s, w3z, inter);

    if (ws_size >= base + 4 * pbytes) {
        gemm_down<4><<<dim3(4, H_DIM / 64, 4), dim3(256), 0, stream>>>(inter, w2q, w2s, w2z, parts);
        reduce_kernel<4><<<dim3(2048), dim3(256), 0, stream>>>(parts, (float*)d_out);
    } else if (ws_size >= base + 2 * pbytes) {
        gemm_down<2><<<dim3(4, H_DIM / 64, 2), dim3(256), 0, stream>>>(inter, w2q, w2s, w2z, parts);
        reduce_kernel<2><<<dim3(2048), dim3(256), 0, stream>>>(parts, (float*)d_out);
    } else {
        gemm_down<1><<<dim3(4, H_DIM / 64, 1), dim3(256), 0, stream>>>(inter, w2q, w2s, w2z, parts);
        reduce_kernel<1><<<dim3(2048), dim3(256), 0, stream>>>(parts, (float*)d_out);
    }
}